// Round 2
// baseline (4799.013 us; speedup 1.0000x reference)
//
#include <hip/hip_runtime.h>

#define D 100
#define TT 2048
#define BB 128
#define CHUNK 64
#define NCHUNK (TT / CHUNK)

static __device__ __constant__ float KLO = 2.8853900817779268f;   // 2*log2(e)
static __device__ __constant__ float MKF = -2.8853900817779268f;  // -2*log2(e)

// q += dpp_shuffle(q); ctrl must be an immediate
#define DPP_ADD(q, ctrl)                                                      \
  q += __int_as_float(__builtin_amdgcn_update_dpp(                            \
      0, __float_as_int(q), ctrl, 0xF, 0xF, true))

// ---------------------------------------------------------------------------
// K1: ab2m[j] = -log2(e) * (pos_table[j] . w_ap + b0)
// ---------------------------------------------------------------------------
__global__ void k1_pos(const float* __restrict__ pos, const float* __restrict__ wap,
                       const float* __restrict__ bb, float* __restrict__ ab2m) {
  int j = blockIdx.x * blockDim.x + threadIdx.x;
  if (j < TT) {
    float a = 0.f;
    #pragma unroll 4
    for (int e = 0; e < D; ++e) a = fmaf(pos[j * D + e], wap[e], a);
    ab2m[j] = -1.4426950408889634f * (a + bb[0]);
  }
}

// ---------------------------------------------------------------------------
// Fused producer/consumer scan. One block (512 thr = 8 waves) per batch row.
// wave 0: sequential chain.  waves 1..7: compute g_j = w_r @ h_j into LDS.
// __launch_bounds__(512,1): grid is 128 blocks on 256 CUs, so we never need
// >1 block/CU; give the allocator the full VGPR file so the producers'
// 200-element w_r register arrays do NOT spill (R1: (512,2) capped at 128
// VGPRs -> 4.5 GB of scratch traffic, 4750 us).
// ---------------------------------------------------------------------------
__global__ void __launch_bounds__(512, 1)
sp_scan(const float* __restrict__ h, const float* __restrict__ dv,
        const float* __restrict__ w_c, const float* __restrict__ w_s,
        const float* __restrict__ w_r, const float* __restrict__ ab2m,
        float* __restrict__ out) {
  __shared__ float gbuf[2][CHUNK][128];  // 64 KiB, double-buffered g chunks
  const int b = blockIdx.x;
  const int tid = (int)threadIdx.x;
  const int lane = tid & 63;
  const int wvu = __builtin_amdgcn_readfirstlane(tid) >> 6;  // uniform wave id
  float* crow_s = &gbuf[0][0][0];

  // ---- phase 1: crow[e] = w_c[e] + (d_b @ w_s)[e] - colsum(w_r)[e] --------
  if (tid < 128) {
    float acc = 0.f;
    if (tid < D) {
      float a1 = 0.f, a2 = 0.f;
      for (int dd = 0; dd < D; ++dd) {
        a1 = fmaf(dv[b * D + dd], w_s[dd * D + tid], a1);
        a2 += w_r[dd * D + tid];
      }
      acc = w_c[tid] + a1 - a2;
    }
    crow_s[tid] = acc;
  }
  __syncthreads();

  // ---- phase 2: producers pull their two w_r rows into registers ----------
  float wlo[D], whi[D];
  if (wvu != 0) {
    const float* rl = w_r + lane * D;
    #pragma unroll
    for (int e = 0; e < D; ++e) wlo[e] = rl[e];
    if (lane < 36) {
      const float* rh = w_r + (lane + 64) * D;
      #pragma unroll
      for (int e = 0; e < D; ++e) whi[e] = rh[e];
    } else if (lane == 36) {
      #pragma unroll
      for (int e = 0; e < D; ++e) whi[e] = crow_s[e];  // synthetic row 100
    } else {
      #pragma unroll
      for (int e = 0; e < D; ++e) whi[e] = 0.f;        // pad rows 101..127
    }
  }
  __syncthreads();

  const float* hb = h + (size_t)b * TT * D;

  // consumer state
  float Slo = 0.f, Shi = 0.f, c = 0.f, hlp = 0.f, hhp = 0.f, pout = 0.f;
  float hlb[8], hhb[8], abb[8];

  // ---- phase 3: prime — producers fill chunk 0; consumer prefetches h -----
  if (wvu == 0) {
    __builtin_amdgcn_s_setprio(1);  // favor the latency-critical wave
    #pragma unroll
    for (int i = 0; i < 8; ++i) {
      float sc = (i == 0) ? 0.f : KLO;  // mask t=0 state update
      hlb[i] = sc * hb[(size_t)i * D + lane];
      hhb[i] = (lane < 36) ? sc * hb[(size_t)i * D + lane + 64] : 0.f;
      abb[i] = ab2m[i];
    }
  } else {
    for (int s = wvu - 1; s < CHUNK; s += 7) {
      const float4* hr = (const float4*)(hb + (size_t)s * D);
      float a0 = 0.f, a1 = 0.f, c0 = 0.f, c1 = 0.f;
      #pragma unroll
      for (int qd = 0; qd < 25; ++qd) {
        const float4 hv = hr[qd];
        a0 = fmaf(hv.x, wlo[4 * qd + 0], a0);
        a1 = fmaf(hv.y, wlo[4 * qd + 1], a1);
        a0 = fmaf(hv.z, wlo[4 * qd + 2], a0);
        a1 = fmaf(hv.w, wlo[4 * qd + 3], a1);
        c0 = fmaf(hv.x, whi[4 * qd + 0], c0);
        c1 = fmaf(hv.y, whi[4 * qd + 1], c1);
        c0 = fmaf(hv.z, whi[4 * qd + 2], c0);
        c1 = fmaf(hv.w, whi[4 * qd + 3], c1);
      }
      gbuf[0][s][lane] = a0 + a1;
      gbuf[0][s][lane + 64] = c0 + c1;
    }
  }
  __syncthreads();

  // ---- main loop: 32 chunks of 64 steps -----------------------------------
  for (int cc = 0; cc < NCHUNK; ++cc) {
    if (wvu == 0) {
      float(*gb)[128] = gbuf[cc & 1];
      float g0l = gb[0][lane], g0h = gb[0][lane + 64];
      float g1l = gb[1][lane], g1h = gb[1][lane + 64];
      #pragma unroll 8
      for (int s = 0; s < CHUNK; ++s) {
        const int j = cc * CHUNK + s;
        // grab prefetched values (h used NEXT iter; ab used this iter)
        float hlv = hlb[s & 7], hhv = hhb[s & 7], abv = abb[s & 7];
        // refill slot with j+8 (clamped; clamped values are never consumed)
        {
          int jn = j + 8;
          if (jn >= TT) jn = TT - 1;
          const size_t off = (size_t)jn * D;
          hlb[s & 7] = KLO * hb[off + lane];
          hhb[s & 7] = (lane < 36) ? KLO * hb[off + lane + 64] : 0.f;
          abb[s & 7] = ab2m[jn];
        }
        // LDS g prefetch, distance 2
        float g2l = 0.f, g2h = 0.f;
        if (s < CHUNK - 2) { g2l = gb[s + 2][lane]; g2h = gb[s + 2][lane + 64]; }

        // ---- the sequential chain ----
        Slo = fmaf(hlp, c, Slo);          // deferred state update (h_{j-1}*p_{j-1})
        Shi = fmaf(hhp, c, Shi);
        float rlo = __builtin_amdgcn_rcpf(1.f + __builtin_amdgcn_exp2f(Slo));
        float rhi = __builtin_amdgcn_rcpf(1.f + __builtin_amdgcn_exp2f(Shi));
        float q = rlo * g0l;
        q = fmaf(rhi, g0h, q);
        DPP_ADD(q, 0xB1);   // + lane^1   (quad_perm [1,0,3,2])
        DPP_ADD(q, 0x4E);   // + lane^2   (quad_perm [2,3,0,1])
        DPP_ADD(q, 0x141);  // + lane^7   (row_half_mirror) -> 8-sums
        DPP_ADD(q, 0x140);  // + lane^15  (row_mirror)      -> 16-sums
        const int qi = __float_as_int(q);
        float ra = __int_as_float(__builtin_amdgcn_readlane(qi, 0)) +
                   __int_as_float(__builtin_amdgcn_readlane(qi, 16));
        float rb = __int_as_float(__builtin_amdgcn_readlane(qi, 32)) +
                   __int_as_float(__builtin_amdgcn_readlane(qi, 48));
        float R = ra + rb;                      // = sum_d r_d * g_d  (128 pads incl.)
        float nz = fmaf(MKF, R, abv);           // -log2e * z
        float p = __builtin_amdgcn_rcpf(1.f + __builtin_amdgcn_exp2f(nz));
        pout = (lane == s) ? p : pout;
        c = p;
        hlp = hlv;
        hhp = hhv;
        g0l = g1l; g0h = g1h; g1l = g2l; g1h = g2h;
      }
      out[(size_t)b * TT + cc * CHUNK + lane] = pout;
    } else if (cc + 1 < NCHUNK) {
      float(*gw)[128] = gbuf[(cc + 1) & 1];
      for (int s = wvu - 1; s < CHUNK; s += 7) {
        const int j = (cc + 1) * CHUNK + s;
        const float4* hr = (const float4*)(hb + (size_t)j * D);
        float a0 = 0.f, a1 = 0.f, c0 = 0.f, c1 = 0.f;
        #pragma unroll
        for (int qd = 0; qd < 25; ++qd) {
          const float4 hv = hr[qd];
          a0 = fmaf(hv.x, wlo[4 * qd + 0], a0);
          a1 = fmaf(hv.y, wlo[4 * qd + 1], a1);
          a0 = fmaf(hv.z, wlo[4 * qd + 2], a0);
          a1 = fmaf(hv.w, wlo[4 * qd + 3], a1);
          c0 = fmaf(hv.x, whi[4 * qd + 0], c0);
          c1 = fmaf(hv.y, whi[4 * qd + 1], c1);
          c0 = fmaf(hv.z, whi[4 * qd + 2], c0);
          c1 = fmaf(hv.w, whi[4 * qd + 3], c1);
        }
        gw[s][lane] = a0 + a1;
        gw[s][lane + 64] = c0 + c1;
      }
    }
    __syncthreads();
  }
}

extern "C" void kernel_launch(void* const* d_in, const int* in_sizes, int n_in,
                              void* d_out, int out_size, void* d_ws, size_t ws_size,
                              hipStream_t stream) {
  const float* h   = (const float*)d_in[0];
  const float* dv  = (const float*)d_in[1];
  const float* w_c = (const float*)d_in[2];
  const float* w_s = (const float*)d_in[3];
  const float* w_r = (const float*)d_in[4];
  const float* pos = (const float*)d_in[5];
  const float* wap = (const float*)d_in[6];
  const float* bb  = (const float*)d_in[7];
  float* out = (float*)d_out;
  float* ab2m = (float*)d_ws;  // 2048 floats

  hipLaunchKernelGGL(k1_pos, dim3(TT / 256), dim3(256), 0, stream, pos, wap, bb, ab2m);
  hipLaunchKernelGGL(sp_scan, dim3(BB), dim3(512), 0, stream,
                     h, dv, w_c, w_s, w_r, ab2m, out);
}

// Round 3
// 4735.133 us; speedup vs baseline: 1.0135x; 1.0135x over previous
//
#include <hip/hip_runtime.h>

#define D 100
#define TT 2048
#define BB 128
#define CHUNK 64
#define NCHUNK (TT / CHUNK)

static __device__ __constant__ float KLO = 2.8853900817779268f;   // 2*log2(e)
static __device__ __constant__ float MKF = -2.8853900817779268f;  // -2*log2(e)

// q += dpp_shuffle(q); ctrl must be an immediate
#define DPP_ADD(q, ctrl)                                                      \
  q += __int_as_float(__builtin_amdgcn_update_dpp(                            \
      0, __float_as_int(q), ctrl, 0xF, 0xF, true))

// ---------------------------------------------------------------------------
// K1: ab2m[j] = -log2(e) * (pos_table[j] . w_ap + b0)
// ---------------------------------------------------------------------------
__global__ void k1_pos(const float* __restrict__ pos, const float* __restrict__ wap,
                       const float* __restrict__ bb, float* __restrict__ ab2m) {
  int j = blockIdx.x * blockDim.x + threadIdx.x;
  if (j < TT) {
    float a = 0.f;
    #pragma unroll 4
    for (int e = 0; e < D; ++e) a = fmaf(pos[j * D + e], wap[e], a);
    ab2m[j] = -1.4426950408889634f * (a + bb[0]);
  }
}

// ---------------------------------------------------------------------------
// Fused producer/consumer scan. One block (512 thr = 8 waves) per batch row.
// wave 0: sequential chain.  waves 1..7: compute g_j = w_r @ h_j into LDS.
//
// Register budget: LLVM sets the VGPR budget from
//   Occupancy = min(waves_per_eu_MAX, LDS-derived occupancy).
// 64 KiB LDS -> 2 WGs/CU -> 4 waves/EU -> budget 128 -> the producers'
// 200-float w_r arrays spilled (R1/R2: 4.5 GB scratch reads, 4750 us).
// amdgpu_waves_per_eu(2,2) caps the MAX at 2 waves/EU -> budget 256 VGPRs.
// (launch_bounds' 2nd arg only raises the MIN - useless here.)
// Grid is 128 blocks on 256 CUs, so occupancy above 1 block/CU is moot.
// ---------------------------------------------------------------------------
__attribute__((amdgpu_waves_per_eu(2, 2)))
__global__ void __launch_bounds__(512)
sp_scan(const float* __restrict__ h, const float* __restrict__ dv,
        const float* __restrict__ w_c, const float* __restrict__ w_s,
        const float* __restrict__ w_r, const float* __restrict__ ab2m,
        float* __restrict__ out) {
  __shared__ float gbuf[2][CHUNK][128];  // 64 KiB, double-buffered g chunks
  const int b = blockIdx.x;
  const int tid = (int)threadIdx.x;
  const int lane = tid & 63;
  const int wvu = __builtin_amdgcn_readfirstlane(tid) >> 6;  // uniform wave id
  float* crow_s = &gbuf[0][0][0];

  // ---- phase 1: crow[e] = w_c[e] + (d_b @ w_s)[e] - colsum(w_r)[e] --------
  if (tid < 128) {
    float acc = 0.f;
    if (tid < D) {
      float a1 = 0.f, a2 = 0.f;
      for (int dd = 0; dd < D; ++dd) {
        a1 = fmaf(dv[b * D + dd], w_s[dd * D + tid], a1);
        a2 += w_r[dd * D + tid];
      }
      acc = w_c[tid] + a1 - a2;
    }
    crow_s[tid] = acc;
  }
  __syncthreads();

  // ---- phase 2: producers pull their two w_r rows into registers ----------
  float wlo[D], whi[D];
  if (wvu != 0) {
    const float* rl = w_r + lane * D;
    #pragma unroll
    for (int e = 0; e < D; ++e) wlo[e] = rl[e];
    if (lane < 36) {
      const float* rh = w_r + (lane + 64) * D;
      #pragma unroll
      for (int e = 0; e < D; ++e) whi[e] = rh[e];
    } else if (lane == 36) {
      #pragma unroll
      for (int e = 0; e < D; ++e) whi[e] = crow_s[e];  // synthetic row 100
    } else {
      #pragma unroll
      for (int e = 0; e < D; ++e) whi[e] = 0.f;        // pad rows 101..127
    }
  }
  __syncthreads();

  const float* hb = h + (size_t)b * TT * D;

  // consumer state
  float Slo = 0.f, Shi = 0.f, c = 0.f, hlp = 0.f, hhp = 0.f, pout = 0.f;
  float hlb[8], hhb[8], abb[8];

  // ---- phase 3: prime — producers fill chunk 0; consumer prefetches h -----
  if (wvu == 0) {
    __builtin_amdgcn_s_setprio(1);  // favor the latency-critical wave
    #pragma unroll
    for (int i = 0; i < 8; ++i) {
      float sc = (i == 0) ? 0.f : KLO;  // mask t=0 state update
      hlb[i] = sc * hb[(size_t)i * D + lane];
      hhb[i] = (lane < 36) ? sc * hb[(size_t)i * D + lane + 64] : 0.f;
      abb[i] = ab2m[i];
    }
  } else {
    for (int s = wvu - 1; s < CHUNK; s += 7) {
      const float4* hr = (const float4*)(hb + (size_t)s * D);
      float a0 = 0.f, a1 = 0.f, c0 = 0.f, c1 = 0.f;
      #pragma unroll
      for (int qd = 0; qd < 25; ++qd) {
        const float4 hv = hr[qd];
        a0 = fmaf(hv.x, wlo[4 * qd + 0], a0);
        a1 = fmaf(hv.y, wlo[4 * qd + 1], a1);
        a0 = fmaf(hv.z, wlo[4 * qd + 2], a0);
        a1 = fmaf(hv.w, wlo[4 * qd + 3], a1);
        c0 = fmaf(hv.x, whi[4 * qd + 0], c0);
        c1 = fmaf(hv.y, whi[4 * qd + 1], c1);
        c0 = fmaf(hv.z, whi[4 * qd + 2], c0);
        c1 = fmaf(hv.w, whi[4 * qd + 3], c1);
      }
      gbuf[0][s][lane] = a0 + a1;
      gbuf[0][s][lane + 64] = c0 + c1;
    }
  }
  __syncthreads();

  // ---- main loop: 32 chunks of 64 steps -----------------------------------
  for (int cc = 0; cc < NCHUNK; ++cc) {
    if (wvu == 0) {
      float(*gb)[128] = gbuf[cc & 1];
      float g0l = gb[0][lane], g0h = gb[0][lane + 64];
      float g1l = gb[1][lane], g1h = gb[1][lane + 64];
      #pragma unroll 8
      for (int s = 0; s < CHUNK; ++s) {
        const int j = cc * CHUNK + s;
        // grab prefetched values (h used NEXT iter; ab used this iter)
        float hlv = hlb[s & 7], hhv = hhb[s & 7], abv = abb[s & 7];
        // refill slot with j+8 (clamped; clamped values are never consumed)
        {
          int jn = j + 8;
          if (jn >= TT) jn = TT - 1;
          const size_t off = (size_t)jn * D;
          hlb[s & 7] = KLO * hb[off + lane];
          hhb[s & 7] = (lane < 36) ? KLO * hb[off + lane + 64] : 0.f;
          abb[s & 7] = ab2m[jn];
        }
        // LDS g prefetch, distance 2
        float g2l = 0.f, g2h = 0.f;
        if (s < CHUNK - 2) { g2l = gb[s + 2][lane]; g2h = gb[s + 2][lane + 64]; }

        // ---- the sequential chain ----
        Slo = fmaf(hlp, c, Slo);          // deferred state update (h_{j-1}*p_{j-1})
        Shi = fmaf(hhp, c, Shi);
        float rlo = __builtin_amdgcn_rcpf(1.f + __builtin_amdgcn_exp2f(Slo));
        float rhi = __builtin_amdgcn_rcpf(1.f + __builtin_amdgcn_exp2f(Shi));
        float q = rlo * g0l;
        q = fmaf(rhi, g0h, q);
        DPP_ADD(q, 0xB1);   // + lane^1   (quad_perm [1,0,3,2])
        DPP_ADD(q, 0x4E);   // + lane^2   (quad_perm [2,3,0,1])
        DPP_ADD(q, 0x141);  // + lane^7   (row_half_mirror) -> 8-sums
        DPP_ADD(q, 0x140);  // + lane^15  (row_mirror)      -> 16-sums
        const int qi = __float_as_int(q);
        float ra = __int_as_float(__builtin_amdgcn_readlane(qi, 0)) +
                   __int_as_float(__builtin_amdgcn_readlane(qi, 16));
        float rb = __int_as_float(__builtin_amdgcn_readlane(qi, 32)) +
                   __int_as_float(__builtin_amdgcn_readlane(qi, 48));
        float R = ra + rb;                      // = sum_d r_d * g_d  (128 pads incl.)
        float nz = fmaf(MKF, R, abv);           // -log2e * z
        float p = __builtin_amdgcn_rcpf(1.f + __builtin_amdgcn_exp2f(nz));
        pout = (lane == s) ? p : pout;
        c = p;
        hlp = hlv;
        hhp = hhv;
        g0l = g1l; g0h = g1h; g1l = g2l; g1h = g2h;
      }
      out[(size_t)b * TT + cc * CHUNK + lane] = pout;
    } else if (cc + 1 < NCHUNK) {
      float(*gw)[128] = gbuf[(cc + 1) & 1];
      for (int s = wvu - 1; s < CHUNK; s += 7) {
        const int j = (cc + 1) * CHUNK + s;
        const float4* hr = (const float4*)(hb + (size_t)j * D);
        float a0 = 0.f, a1 = 0.f, c0 = 0.f, c1 = 0.f;
        #pragma unroll
        for (int qd = 0; qd < 25; ++qd) {
          const float4 hv = hr[qd];
          a0 = fmaf(hv.x, wlo[4 * qd + 0], a0);
          a1 = fmaf(hv.y, wlo[4 * qd + 1], a1);
          a0 = fmaf(hv.z, wlo[4 * qd + 2], a0);
          a1 = fmaf(hv.w, wlo[4 * qd + 3], a1);
          c0 = fmaf(hv.x, whi[4 * qd + 0], c0);
          c1 = fmaf(hv.y, whi[4 * qd + 1], c1);
          c0 = fmaf(hv.z, whi[4 * qd + 2], c0);
          c1 = fmaf(hv.w, whi[4 * qd + 3], c1);
        }
        gw[s][lane] = a0 + a1;
        gw[s][lane + 64] = c0 + c1;
      }
    }
    __syncthreads();
  }
}

extern "C" void kernel_launch(void* const* d_in, const int* in_sizes, int n_in,
                              void* d_out, int out_size, void* d_ws, size_t ws_size,
                              hipStream_t stream) {
  const float* h   = (const float*)d_in[0];
  const float* dv  = (const float*)d_in[1];
  const float* w_c = (const float*)d_in[2];
  const float* w_s = (const float*)d_in[3];
  const float* w_r = (const float*)d_in[4];
  const float* pos = (const float*)d_in[5];
  const float* wap = (const float*)d_in[6];
  const float* bb  = (const float*)d_in[7];
  float* out = (float*)d_out;
  float* ab2m = (float*)d_ws;  // 2048 floats

  hipLaunchKernelGGL(k1_pos, dim3(TT / 256), dim3(256), 0, stream, pos, wap, bb, ab2m);
  hipLaunchKernelGGL(sp_scan, dim3(BB), dim3(512), 0, stream,
                     h, dv, w_c, w_s, w_r, ab2m, out);
}

// Round 4
// 4713.462 us; speedup vs baseline: 1.0182x; 1.0046x over previous
//
#include <hip/hip_runtime.h>

#define D 100
#define TT 2048
#define BB 128
#define CHUNK 64
#define NCHUNK (TT / CHUNK)

static __device__ __constant__ float KLO = 2.8853900817779268f;   // 2*log2(e)
static __device__ __constant__ float MKF = -2.8853900817779268f;  // -2*log2(e)

// q += dpp_shuffle(q); ctrl must be an immediate
#define DPP_ADD(q, ctrl)                                                      \
  q += __int_as_float(__builtin_amdgcn_update_dpp(                            \
      0, __float_as_int(q), ctrl, 0xF, 0xF, true))

// ---------------------------------------------------------------------------
// K1: ab2m[j] = -log2(e) * (pos_table[j] . w_ap + b0)
// ---------------------------------------------------------------------------
__global__ void k1_pos(const float* __restrict__ pos, const float* __restrict__ wap,
                       const float* __restrict__ bb, float* __restrict__ ab2m) {
  int j = blockIdx.x * blockDim.x + threadIdx.x;
  if (j < TT) {
    float a = 0.f;
    #pragma unroll 4
    for (int e = 0; e < D; ++e) a = fmaf(pos[j * D + e], wap[e], a);
    ab2m[j] = -1.4426950408889634f * (a + bb[0]);
  }
}

// ---------------------------------------------------------------------------
// Fused producer/consumer scan. One block (512 thr = 8 waves) per batch row.
// wave 0: sequential chain.  waves 1..7: compute g_j = w_r @ h_j into LDS.
//
// VGPR-budget mechanism (R1-R3 post-mortem): the backend's register budget is
// set by the LDS-derived occupancy target. 64 KiB LDS -> 2 WGs/CU -> 4
// waves/EU -> budget 128 VGPRs -> the producers' 200-float w_r arrays spilled
// (4.5 GB/dispatch scratch reloads, 4750 us). Neither __launch_bounds__' 2nd
// arg nor amdgpu_waves_per_eu lowered that target in R2/R3. So we pad LDS to
// 96 KiB: floor(160/96) = 1 WG/CU -> 8 waves/CU -> 2 waves/EU -> budget >=256
// VGPRs. Free, since grid = 128 blocks on 256 CUs (1 block/CU regardless).
// ---------------------------------------------------------------------------
__global__ void __launch_bounds__(512)
__attribute__((amdgpu_waves_per_eu(2, 2)))
sp_scan(const float* __restrict__ h, const float* __restrict__ dv,
        const float* __restrict__ w_c, const float* __restrict__ w_s,
        const float* __restrict__ w_r, const float* __restrict__ ab2m,
        float* __restrict__ out) {
  __shared__ float gbuf[2][CHUNK][128];  // 64 KiB, double-buffered g chunks
  __shared__ float pad_lds[8192];        // +32 KiB: occupancy->1 WG/CU (see above)
  const int b = blockIdx.x;
  const int tid = (int)threadIdx.x;
  const int lane = tid & 63;
  const int wvu = __builtin_amdgcn_readfirstlane(tid) >> 6;  // uniform wave id
  float* crow_s = &pad_lds[0];  // crow staging lives in the pad (keeps it live)

  // ---- phase 1: crow[e] = w_c[e] + (d_b @ w_s)[e] - colsum(w_r)[e] --------
  if (tid < 128) {
    float acc = 0.f;
    if (tid < D) {
      float a1 = 0.f, a2 = 0.f;
      for (int dd = 0; dd < D; ++dd) {
        a1 = fmaf(dv[b * D + dd], w_s[dd * D + tid], a1);
        a2 += w_r[dd * D + tid];
      }
      acc = w_c[tid] + a1 - a2;
    }
    crow_s[tid] = acc;
  }
  __syncthreads();

  // ---- phase 2: producers pull their two w_r rows into registers ----------
  float wlo[D], whi[D];
  if (wvu != 0) {
    const float* rl = w_r + lane * D;
    #pragma unroll
    for (int e = 0; e < D; ++e) wlo[e] = rl[e];
    if (lane < 36) {
      const float* rh = w_r + (lane + 64) * D;
      #pragma unroll
      for (int e = 0; e < D; ++e) whi[e] = rh[e];
    } else if (lane == 36) {
      #pragma unroll
      for (int e = 0; e < D; ++e) whi[e] = crow_s[e];  // synthetic row 100
    } else {
      #pragma unroll
      for (int e = 0; e < D; ++e) whi[e] = 0.f;        // pad rows 101..127
    }
  }
  __syncthreads();

  const float* hb = h + (size_t)b * TT * D;

  // consumer state
  float Slo = 0.f, Shi = 0.f, c = 0.f, hlp = 0.f, hhp = 0.f, pout = 0.f;
  float hlb[8], hhb[8], abb[8];

  // ---- phase 3: prime — producers fill chunk 0; consumer prefetches h -----
  if (wvu == 0) {
    __builtin_amdgcn_s_setprio(1);  // favor the latency-critical wave
    #pragma unroll
    for (int i = 0; i < 8; ++i) {
      float sc = (i == 0) ? 0.f : KLO;  // mask t=0 state update
      hlb[i] = sc * hb[(size_t)i * D + lane];
      hhb[i] = (lane < 36) ? sc * hb[(size_t)i * D + lane + 64] : 0.f;
      abb[i] = ab2m[i];
    }
  } else {
    for (int s = wvu - 1; s < CHUNK; s += 7) {
      const float4* hr = (const float4*)(hb + (size_t)s * D);
      float a0 = 0.f, a1 = 0.f, c0 = 0.f, c1 = 0.f;
      #pragma unroll
      for (int qd = 0; qd < 25; ++qd) {
        const float4 hv = hr[qd];
        a0 = fmaf(hv.x, wlo[4 * qd + 0], a0);
        a1 = fmaf(hv.y, wlo[4 * qd + 1], a1);
        a0 = fmaf(hv.z, wlo[4 * qd + 2], a0);
        a1 = fmaf(hv.w, wlo[4 * qd + 3], a1);
        c0 = fmaf(hv.x, whi[4 * qd + 0], c0);
        c1 = fmaf(hv.y, whi[4 * qd + 1], c1);
        c0 = fmaf(hv.z, whi[4 * qd + 2], c0);
        c1 = fmaf(hv.w, whi[4 * qd + 3], c1);
      }
      gbuf[0][s][lane] = a0 + a1;
      gbuf[0][s][lane + 64] = c0 + c1;
    }
  }
  __syncthreads();

  // ---- main loop: 32 chunks of 64 steps -----------------------------------
  for (int cc = 0; cc < NCHUNK; ++cc) {
    if (wvu == 0) {
      float(*gb)[128] = gbuf[cc & 1];
      float g0l = gb[0][lane], g0h = gb[0][lane + 64];
      float g1l = gb[1][lane], g1h = gb[1][lane + 64];
      #pragma unroll 8
      for (int s = 0; s < CHUNK; ++s) {
        const int j = cc * CHUNK + s;
        // grab prefetched values (h used NEXT iter; ab used this iter)
        float hlv = hlb[s & 7], hhv = hhb[s & 7], abv = abb[s & 7];
        // refill slot with j+8 (clamped; clamped values are never consumed)
        {
          int jn = j + 8;
          if (jn >= TT) jn = TT - 1;
          const size_t off = (size_t)jn * D;
          hlb[s & 7] = KLO * hb[off + lane];
          hhb[s & 7] = (lane < 36) ? KLO * hb[off + lane + 64] : 0.f;
          abb[s & 7] = ab2m[jn];
        }
        // LDS g prefetch, distance 2
        float g2l = 0.f, g2h = 0.f;
        if (s < CHUNK - 2) { g2l = gb[s + 2][lane]; g2h = gb[s + 2][lane + 64]; }

        // ---- the sequential chain ----
        Slo = fmaf(hlp, c, Slo);          // deferred state update (h_{j-1}*p_{j-1})
        Shi = fmaf(hhp, c, Shi);
        float rlo = __builtin_amdgcn_rcpf(1.f + __builtin_amdgcn_exp2f(Slo));
        float rhi = __builtin_amdgcn_rcpf(1.f + __builtin_amdgcn_exp2f(Shi));
        float q = rlo * g0l;
        q = fmaf(rhi, g0h, q);
        DPP_ADD(q, 0xB1);   // + lane^1   (quad_perm [1,0,3,2])
        DPP_ADD(q, 0x4E);   // + lane^2   (quad_perm [2,3,0,1])
        DPP_ADD(q, 0x141);  // + lane^7   (row_half_mirror) -> 8-sums
        DPP_ADD(q, 0x140);  // + lane^15  (row_mirror)      -> 16-sums
        const int qi = __float_as_int(q);
        float ra = __int_as_float(__builtin_amdgcn_readlane(qi, 0)) +
                   __int_as_float(__builtin_amdgcn_readlane(qi, 16));
        float rb = __int_as_float(__builtin_amdgcn_readlane(qi, 32)) +
                   __int_as_float(__builtin_amdgcn_readlane(qi, 48));
        float R = ra + rb;                      // = sum_d r_d * g_d  (128 pads incl.)
        float nz = fmaf(MKF, R, abv);           // -log2e * z
        float p = __builtin_amdgcn_rcpf(1.f + __builtin_amdgcn_exp2f(nz));
        pout = (lane == s) ? p : pout;
        c = p;
        hlp = hlv;
        hhp = hhv;
        g0l = g1l; g0h = g1h; g1l = g2l; g1h = g2h;
      }
      out[(size_t)b * TT + cc * CHUNK + lane] = pout;
    } else if (cc + 1 < NCHUNK) {
      float(*gw)[128] = gbuf[(cc + 1) & 1];
      for (int s = wvu - 1; s < CHUNK; s += 7) {
        const int j = (cc + 1) * CHUNK + s;
        const float4* hr = (const float4*)(hb + (size_t)j * D);
        float a0 = 0.f, a1 = 0.f, c0 = 0.f, c1 = 0.f;
        #pragma unroll
        for (int qd = 0; qd < 25; ++qd) {
          const float4 hv = hr[qd];
          a0 = fmaf(hv.x, wlo[4 * qd + 0], a0);
          a1 = fmaf(hv.y, wlo[4 * qd + 1], a1);
          a0 = fmaf(hv.z, wlo[4 * qd + 2], a0);
          a1 = fmaf(hv.w, wlo[4 * qd + 3], a1);
          c0 = fmaf(hv.x, whi[4 * qd + 0], c0);
          c1 = fmaf(hv.y, whi[4 * qd + 1], c1);
          c0 = fmaf(hv.z, whi[4 * qd + 2], c0);
          c1 = fmaf(hv.w, whi[4 * qd + 3], c1);
        }
        gw[s][lane] = a0 + a1;
        gw[s][lane + 64] = c0 + c1;
      }
    }
    __syncthreads();
  }
}

extern "C" void kernel_launch(void* const* d_in, const int* in_sizes, int n_in,
                              void* d_out, int out_size, void* d_ws, size_t ws_size,
                              hipStream_t stream) {
  const float* h   = (const float*)d_in[0];
  const float* dv  = (const float*)d_in[1];
  const float* w_c = (const float*)d_in[2];
  const float* w_s = (const float*)d_in[3];
  const float* w_r = (const float*)d_in[4];
  const float* pos = (const float*)d_in[5];
  const float* wap = (const float*)d_in[6];
  const float* bb  = (const float*)d_in[7];
  float* out = (float*)d_out;
  float* ab2m = (float*)d_ws;  // 2048 floats

  hipLaunchKernelGGL(k1_pos, dim3(TT / 256), dim3(256), 0, stream, pos, wap, bb, ab2m);
  hipLaunchKernelGGL(sp_scan, dim3(BB), dim3(512), 0, stream,
                     h, dv, w_c, w_s, w_r, ab2m, out);
}

// Round 5
// 552.568 us; speedup vs baseline: 8.6849x; 8.5301x over previous
//
#include <hip/hip_runtime.h>

#define D 100
#define TT 2048
#define BB 128
#define CHUNK 64
#define NCHUNK (TT / CHUNK)
#define NTHR 832  /* 13 waves: wave0 consumer, waves 1..12 producers */

static __device__ __constant__ float KLO = 2.8853900817779268f;   // 2*log2(e)
static __device__ __constant__ float MKF = -2.8853900817779268f;  // -2*log2(e)

// q += dpp_shuffle(q); ctrl must be an immediate
#define DPP_ADD(q, ctrl)                                                      \
  q += __int_as_float(__builtin_amdgcn_update_dpp(                            \
      0, __float_as_int(q), ctrl, 0xF, 0xF, true))

// ---------------------------------------------------------------------------
// K1: ab2m[j] = -log2(e) * (pos_table[j] . w_ap + b0)
// ---------------------------------------------------------------------------
__global__ void k1_pos(const float* __restrict__ pos, const float* __restrict__ wap,
                       const float* __restrict__ bb, float* __restrict__ ab2m) {
  int j = blockIdx.x * blockDim.x + threadIdx.x;
  if (j < TT) {
    float a = 0.f;
    #pragma unroll 4
    for (int e = 0; e < D; ++e) a = fmaf(pos[j * D + e], wap[e], a);
    ab2m[j] = -1.4426950408889634f * (a + bb[0]);
  }
}

// Partial dot of a half-row (52 or 48 elements) against h[j][eoff..]
template <int NQ>
__device__ __forceinline__ float prod_dot(const float* wr, const float4* hr) {
  float a0 = 0.f, a1 = 0.f;
  #pragma unroll
  for (int qd = 0; qd < NQ; ++qd) {
    const float4 hv = hr[qd];
    a0 = fmaf(hv.x, wr[4 * qd + 0], a0);
    a1 = fmaf(hv.y, wr[4 * qd + 1], a1);
    a0 = fmaf(hv.z, wr[4 * qd + 2], a0);
    a1 = fmaf(hv.w, wr[4 * qd + 3], a1);
  }
  return a0 + a1;
}

// ---------------------------------------------------------------------------
// Fused producer/consumer scan. One block (832 thr = 13 waves) per batch row.
// wave 0: sequential chain.  waves 1..12: compute g_j = w_r @ h_j into LDS.
//
// R1-R4 post-mortem: the VGPR budget is pinned at 128 (4 waves/EU target; no
// attribute moved it), and allocation is static across waves, so the UNION of
// producer + consumer live sets must fit 128. Old design: 200-float w_r
// arrays per producer lane -> spill -> 4.5 GB scratch traffic -> 4750 us.
// New design: each producer wave holds HALF a w_r row per lane (wr[52], 64
// rows/wave); 4 wave-tasks (2 row-blocks x 2 element-halves, all wave-uniform
// so no divergence) cover the 128 g-slots, writing partial dots to
// gbuf[.][s][256]. Consumer pre-adds the partials at prefetch time (off the
// critical path); its chain is identical to the proven R1 chain.
// Live union ~ 52 + ~45 + temps < 128 -> no spill.
// ---------------------------------------------------------------------------
__global__ void __launch_bounds__(NTHR)
sp_scan(const float* __restrict__ h, const float* __restrict__ dv,
        const float* __restrict__ w_c, const float* __restrict__ w_s,
        const float* __restrict__ w_r, const float* __restrict__ ab2m,
        float* __restrict__ out) {
  __shared__ float gbuf[2][CHUNK][256];  // 128 KiB: two part-planes per buffer
  __shared__ float crow_s[128];
  const int b = blockIdx.x;
  const int tid = (int)threadIdx.x;
  const int lane = tid & 63;
  const int wvu = __builtin_amdgcn_readfirstlane(tid) >> 6;  // uniform wave id

  // producer task decode (wave-uniform): q in [0,12)
  const int q = wvu - 1;
  const int grp = q >> 2;        // timestep group 0..2 (s == grp mod 3)
  const int blk = (q & 3) >> 1;  // row block: rows blk*64 + lane
  const int hf = q & 1;          // element half: [0,52) or [52,100)
  const int eoff = hf ? 52 : 0;
  const int col = hf * 128 + blk * 64 + lane;  // gbuf column for this lane

  // ---- phase 1: crow[e] = w_c[e] + (d_b @ w_s)[e] - colsum(w_r)[e] --------
  if (tid < 128) {
    float acc = 0.f;
    if (tid < D) {
      float a1 = 0.f, a2 = 0.f;
      for (int dd = 0; dd < D; ++dd) {
        a1 = fmaf(dv[b * D + dd], w_s[dd * D + tid], a1);
        a2 += w_r[dd * D + tid];
      }
      acc = w_c[tid] + a1 - a2;
    }
    crow_s[tid] = acc;
  }
  __syncthreads();

  // ---- phase 2: producers pull their half-row into registers --------------
  float wr[52];
  if (wvu != 0) {
    const int row = blk * 64 + lane;  // 0..127
    if (row < D) {
      const float* src = w_r + row * D + eoff;
      if (hf == 0) {
        #pragma unroll
        for (int e = 0; e < 52; ++e) wr[e] = src[e];
      } else {
        #pragma unroll
        for (int e = 0; e < 48; ++e) wr[e] = src[e];
        wr[48] = wr[49] = wr[50] = wr[51] = 0.f;
      }
    } else if (row == D) {  // synthetic row 100 = crow
      if (hf == 0) {
        #pragma unroll
        for (int e = 0; e < 52; ++e) wr[e] = crow_s[e];
      } else {
        #pragma unroll
        for (int e = 0; e < 48; ++e) wr[e] = crow_s[52 + e];
        wr[48] = wr[49] = wr[50] = wr[51] = 0.f;
      }
    } else {  // pad rows 101..127
      #pragma unroll
      for (int e = 0; e < 52; ++e) wr[e] = 0.f;
    }
  }

  const float* hb = h + (size_t)b * TT * D;

  // consumer state
  float Slo = 0.f, Shi = 0.f, c = 0.f, hlp = 0.f, hhp = 0.f, pout = 0.f;
  float hlb[8], hhb[8], abb[8];

  // ---- phase 3: prime — producers fill chunk 0; consumer prefetches h -----
  if (wvu == 0) {
    __builtin_amdgcn_s_setprio(1);  // favor the latency-critical wave
    #pragma unroll
    for (int i = 0; i < 8; ++i) {
      float sc = (i == 0) ? 0.f : KLO;  // mask t=0 state update
      hlb[i] = sc * hb[(size_t)i * D + lane];
      hhb[i] = (lane < 36) ? sc * hb[(size_t)i * D + lane + 64] : 0.f;
      abb[i] = ab2m[i];
    }
  } else {
    for (int s = grp; s < CHUNK; s += 3) {
      const float* hrow = hb + (size_t)s * D + eoff;
      float v;
      if (hf == 0) v = prod_dot<13>(wr, (const float4*)hrow);
      else         v = prod_dot<12>(wr, (const float4*)hrow);
      gbuf[0][s][col] = v;
    }
  }
  __syncthreads();

  // ---- main loop: 32 chunks of 64 steps -----------------------------------
  for (int cc = 0; cc < NCHUNK; ++cc) {
    if (wvu == 0) {
      float(*gb)[256] = gbuf[cc & 1];
      float g0l = gb[0][lane] + gb[0][128 + lane];
      float g0h = gb[0][64 + lane] + gb[0][192 + lane];
      float g1l = gb[1][lane] + gb[1][128 + lane];
      float g1h = gb[1][64 + lane] + gb[1][192 + lane];
      #pragma unroll 8
      for (int s = 0; s < CHUNK; ++s) {
        const int j = cc * CHUNK + s;
        // grab prefetched values (h used NEXT iter; ab used this iter)
        float hlv = hlb[s & 7], hhv = hhb[s & 7], abv = abb[s & 7];
        // refill slot with j+8 (clamped; clamped values are never consumed)
        {
          int jn = j + 8;
          if (jn >= TT) jn = TT - 1;
          const size_t off = (size_t)jn * D;
          hlb[s & 7] = KLO * hb[off + lane];
          hhb[s & 7] = (lane < 36) ? KLO * hb[off + lane + 64] : 0.f;
          abb[s & 7] = ab2m[jn];
        }
        // LDS g prefetch, distance 2 (pre-add the two part-planes here,
        // OFF the critical path)
        float g2l = 0.f, g2h = 0.f;
        if (s < CHUNK - 2) {
          g2l = gb[s + 2][lane] + gb[s + 2][128 + lane];
          g2h = gb[s + 2][64 + lane] + gb[s + 2][192 + lane];
        }

        // ---- the sequential chain ----
        Slo = fmaf(hlp, c, Slo);          // deferred state update (h_{j-1}*p_{j-1})
        Shi = fmaf(hhp, c, Shi);
        float rlo = __builtin_amdgcn_rcpf(1.f + __builtin_amdgcn_exp2f(Slo));
        float rhi = __builtin_amdgcn_rcpf(1.f + __builtin_amdgcn_exp2f(Shi));
        float qq = rlo * g0l;
        qq = fmaf(rhi, g0h, qq);
        DPP_ADD(qq, 0xB1);   // + lane^1   (quad_perm [1,0,3,2])
        DPP_ADD(qq, 0x4E);   // + lane^2   (quad_perm [2,3,0,1])
        DPP_ADD(qq, 0x141);  // + lane^7   (row_half_mirror) -> 8-sums
        DPP_ADD(qq, 0x140);  // + lane^15  (row_mirror)      -> 16-sums
        const int qi = __float_as_int(qq);
        float ra = __int_as_float(__builtin_amdgcn_readlane(qi, 0)) +
                   __int_as_float(__builtin_amdgcn_readlane(qi, 16));
        float rb = __int_as_float(__builtin_amdgcn_readlane(qi, 32)) +
                   __int_as_float(__builtin_amdgcn_readlane(qi, 48));
        float R = ra + rb;                      // = sum_d r_d * g_d
        float nz = fmaf(MKF, R, abv);           // -log2e * z
        float p = __builtin_amdgcn_rcpf(1.f + __builtin_amdgcn_exp2f(nz));
        pout = (lane == s) ? p : pout;
        c = p;
        hlp = hlv;
        hhp = hhv;
        g0l = g1l; g0h = g1h; g1l = g2l; g1h = g2h;
      }
      out[(size_t)b * TT + cc * CHUNK + lane] = pout;
    } else if (cc + 1 < NCHUNK) {
      float(*gw)[256] = gbuf[(cc + 1) & 1];
      const int jbase = (cc + 1) * CHUNK;
      for (int s = grp; s < CHUNK; s += 3) {
        const float* hrow = hb + (size_t)(jbase + s) * D + eoff;
        float v;
        if (hf == 0) v = prod_dot<13>(wr, (const float4*)hrow);
        else         v = prod_dot<12>(wr, (const float4*)hrow);
        gw[s][col] = v;
      }
    }
    __syncthreads();
  }
}

extern "C" void kernel_launch(void* const* d_in, const int* in_sizes, int n_in,
                              void* d_out, int out_size, void* d_ws, size_t ws_size,
                              hipStream_t stream) {
  const float* h   = (const float*)d_in[0];
  const float* dv  = (const float*)d_in[1];
  const float* w_c = (const float*)d_in[2];
  const float* w_s = (const float*)d_in[3];
  const float* w_r = (const float*)d_in[4];
  const float* pos = (const float*)d_in[5];
  const float* wap = (const float*)d_in[6];
  const float* bb  = (const float*)d_in[7];
  float* out = (float*)d_out;
  float* ab2m = (float*)d_ws;  // 2048 floats

  hipLaunchKernelGGL(k1_pos, dim3(TT / 256), dim3(256), 0, stream, pos, wap, bb, ab2m);
  hipLaunchKernelGGL(sp_scan, dim3(BB), dim3(NTHR), 0, stream,
                     h, dv, w_c, w_s, w_r, ab2m, out);
}